// Round 16
// baseline (959.331 us; speedup 1.0000x reference)
//
#include <hip/hip_runtime.h>
#include <math.h>

typedef unsigned short ushort_t;
typedef __attribute__((ext_vector_type(8))) short bf16x8;
typedef __attribute__((ext_vector_type(4))) float f32x4;

constexpr int Bb  = 128;
constexpr int Ll  = 196;
constexpr int ENCe= 512;
constexpr int Hh  = 512;
constexpr int Ee  = 256;
constexpr int Vv  = 10000;
constexpr int Tt  = 20;

#define DEV __device__ __forceinline__

DEV float sigm_f(float x) { return 1.f / (1.f + __expf(-x)); }
DEV float tanh_f(float x) {
    x = fminf(fmaxf(x, -15.f), 15.f);
    float e = __expf(2.f * x);
    return (e - 1.f) / (e + 1.f);
}
DEV ushort_t f2bf(float v) {
    unsigned u = __float_as_uint(v);
    return (ushort_t)((u + 0x7FFFu + ((u >> 16) & 1u)) >> 16);
}
DEV float bf2f(ushort_t h) { return __uint_as_float(((unsigned)h) << 16); }

// Packed-fragment layout for a logical [R][K] bf16 matrix:
//   (r,k) -> ((r>>4)*KS + (k>>5))*512 + (((k>>3)&3)*16 + (r&15))*8 + (k&7)
DEV size_t xh_idx(int b, int k)
{
    return (((size_t)(b >> 4) * 40 + (k >> 5)) * 64
            + ((k >> 3) & 3) * 16 + (b & 15)) * 8 + (k & 7);
}
DEV void store_xh2(ushort_t* __restrict__ H, ushort_t* __restrict__ L,
                   int b, int k, float v)   // hi+lo (h range: dg consumes lo)
{
    size_t idx = xh_idx(b, k);
    ushort_t hb = f2bf(v);
    H[idx] = hb;
    L[idx] = f2bf(v - bf2f(hb));
}
DEV void store_xh1(ushort_t* __restrict__ H, int b, int k, float v) // hi only
{
    H[xh_idx(b, k)] = f2bf(v);
}

// ---------------------------------------------------------------------------
// fp32 tiled GEMM (enc_proj fallback only). OUTBF emits bf16.
// ---------------------------------------------------------------------------
template<int BN, int TM, int TN, int ACT1, int OUTBF>
__global__ __launch_bounds__(256)
void gemm_k(const float* __restrict__ A, int lda,
            const float* __restrict__ Wk, int ldw,
            const float* __restrict__ bias,
            void* __restrict__ Cv, long long ldc,
            int M, int N, int K)
{
    constexpr int BM = 64, BK = 16;
    constexpr int TX = BN / TN, TY = BM / TM;
    static_assert(TX * TY == 256, "bad tile config");
    __shared__ float As[BK][BM];
    __shared__ float Ws[BK][BN];

    const int tid = threadIdx.x;
    const int tx = tid % TX, ty = tid / TX;
    const int nb = blockIdx.x * BN, mb = blockIdx.y * BM;

    float acc[TM][TN] = {};
    const int am = tid >> 2;
    const int ak = (tid & 3) * 4;
    const int wn = tid % BN;
    const int wk0 = tid / BN;
    constexpr int WKSTEP = 256 / BN;

    for (int k0 = 0; k0 < K; k0 += BK) {
        float4 av = *(const float4*)&A[(size_t)(mb + am) * lda + k0 + ak];
        As[ak + 0][am] = av.x;
        As[ak + 1][am] = av.y;
        As[ak + 2][am] = av.z;
        As[ak + 3][am] = av.w;
        #pragma unroll
        for (int i = 0; i < BK / WKSTEP; ++i) {
            int kw = wk0 + i * WKSTEP;
            Ws[kw][wn] = (nb + wn < N) ? Wk[(size_t)(k0 + kw) * ldw + nb + wn] : 0.f;
        }
        __syncthreads();
        #pragma unroll
        for (int k = 0; k < BK; ++k) {
            float a[TM], w[TN];
            #pragma unroll
            for (int i = 0; i < TM; ++i) a[i] = As[k][ty * TM + i];
            #pragma unroll
            for (int j = 0; j < TN; ++j) w[j] = Ws[k][tx * TN + j];
            #pragma unroll
            for (int i = 0; i < TM; ++i)
                #pragma unroll
                for (int j = 0; j < TN; ++j)
                    acc[i][j] = fmaf(a[i], w[j], acc[i][j]);
        }
        __syncthreads();
    }

    #pragma unroll
    for (int i = 0; i < TM; ++i) {
        int m = mb + ty * TM + i;
        #pragma unroll
        for (int j = 0; j < TN; ++j) {
            int n = nb + tx * TN + j;
            if (n < N) {
                float v = acc[i][j];
                if (bias) v += bias[n];
                if (ACT1 == 1) v = tanh_f(v);
                if (OUTBF) ((ushort_t*)Cv)[(size_t)m * ldc + n] = f2bf(v);
                else       ((float*)Cv)[(size_t)m * ldc + n] = v;
            }
        }
    }
}

// ---------------------------------------------------------------------------
// h0/c0 GEMM: grid (16, 4). by&1 = m-block; by>>1 selects W_h->xh / W_c->cbuf
// ---------------------------------------------------------------------------
__global__ __launch_bounds__(256)
void h0c0_k(const float* __restrict__ fm,
            const float* __restrict__ W_h, const float* __restrict__ b_h,
            const float* __restrict__ W_c, const float* __restrict__ b_c,
            ushort_t* __restrict__ xhH, ushort_t* __restrict__ xhL,
            float* __restrict__ cbuf)
{
    constexpr int BM = 64, BK = 16, BN = 32, TM = 2, TN = 4;
    constexpr int TX = BN / TN;
    __shared__ float As[BK][BM];
    __shared__ float Ws[BK][BN];

    const int sel = blockIdx.y >> 1;
    const float* Wk   = sel ? W_c : W_h;
    const float* bias = sel ? b_c : b_h;

    const int tid = threadIdx.x;
    const int tx = tid % TX, ty = tid / TX;
    const int nb = blockIdx.x * BN, mb = (blockIdx.y & 1) * BM;

    float acc[TM][TN] = {};
    const int am = tid >> 2;
    const int ak = (tid & 3) * 4;
    const int wn = tid % BN;
    const int wk0 = tid / BN;
    constexpr int WKSTEP = 256 / BN;

    for (int k0 = 0; k0 < ENCe; k0 += BK) {
        float4 av = *(const float4*)&fm[(size_t)(mb + am) * ENCe + k0 + ak];
        As[ak + 0][am] = av.x;
        As[ak + 1][am] = av.y;
        As[ak + 2][am] = av.z;
        As[ak + 3][am] = av.w;
        #pragma unroll
        for (int i = 0; i < BK / WKSTEP; ++i) {
            int kw = wk0 + i * WKSTEP;
            Ws[kw][wn] = Wk[(size_t)(k0 + kw) * Hh + nb + wn];
        }
        __syncthreads();
        #pragma unroll
        for (int k = 0; k < BK; ++k) {
            float a[TM], w[TN];
            #pragma unroll
            for (int i = 0; i < TM; ++i) a[i] = As[k][ty * TM + i];
            #pragma unroll
            for (int j = 0; j < TN; ++j) w[j] = Ws[k][tx * TN + j];
            #pragma unroll
            for (int i = 0; i < TM; ++i)
                #pragma unroll
                for (int j = 0; j < TN; ++j)
                    acc[i][j] = fmaf(a[i], w[j], acc[i][j]);
        }
        __syncthreads();
    }

    #pragma unroll
    for (int i = 0; i < TM; ++i) {
        int m = mb + ty * TM + i;
        #pragma unroll
        for (int j = 0; j < TN; ++j) {
            int n = nb + tx * TN + j;
            float v = tanh_f(acc[i][j] + bias[n]);
            if (sel) cbuf[(size_t)m * Hh + n] = v;
            else     store_xh2(xhH, xhL, m, 768 + n, v);
        }
    }
}

// ---------------------------------------------------------------------------
// enc_proj GEMM (standalone, 784 blocks): packed split-1, MT=4 NT=4, W2D,
// bijective XCD swizzle (nwg=784, q=98, r=0), n-minor.
// ---------------------------------------------------------------------------
__global__ __launch_bounds__(256)
void enc_k(const ushort_t* __restrict__ AH, const ushort_t* __restrict__ BH,
           const float* __restrict__ bias, ushort_t* __restrict__ C)
{
    constexpr int aFS = 16 * 512;
    const int blk = blockIdx.x;
    const int xcd = blk & 7, idx = blk >> 3;
    const int lin = xcd * 98 + idx;
    const int bx = lin & 3, by = lin >> 2;

    const int wv = threadIdx.x >> 6, lane = threadIdx.x & 63;
    const int nf0 = (bx * 2 + (wv & 1)) * 4;
    const int mf0 = by * 8 + (wv >> 1) * 4;
    const int col = lane & 15;
    const int lofs = lane * 8;

    const ushort_t *paH[4], *pbH[4];
    #pragma unroll
    for (int mt = 0; mt < 4; ++mt) paH[mt] = AH + (size_t)(mf0 + mt) * aFS + lofs;
    #pragma unroll
    for (int ct = 0; ct < 4; ++ct) pbH[ct] = BH + (size_t)(nf0 + ct) * aFS + lofs;

    f32x4 acc[4][4];
    #pragma unroll
    for (int mt = 0; mt < 4; ++mt)
        #pragma unroll
        for (int ct = 0; ct < 4; ++ct) acc[mt][ct] = (f32x4){0.f, 0.f, 0.f, 0.f};

    auto LOADF = [&](bf16x8 (&A0)[4], bf16x8 (&B0)[4], int i) {
        size_t o = (size_t)i * 512;
        #pragma unroll
        for (int mt = 0; mt < 4; ++mt) A0[mt] = *(const bf16x8*)(paH[mt] + o);
        #pragma unroll
        for (int ct = 0; ct < 4; ++ct) B0[ct] = *(const bf16x8*)(pbH[ct] + o);
    };
    auto COMPF = [&](bf16x8 (&A0)[4], bf16x8 (&B0)[4]) {
        #pragma unroll
        for (int mt = 0; mt < 4; ++mt)
            #pragma unroll
            for (int ct = 0; ct < 4; ++ct)
                acc[mt][ct] = __builtin_amdgcn_mfma_f32_16x16x32_bf16(A0[mt], B0[ct], acc[mt][ct], 0, 0, 0);
    };

    bf16x8 xa[4], xb[4], ya[4], yb[4];
    LOADF(xa, xb, 0);
    for (int i = 0; i < 16; i += 2) {
        LOADF(ya, yb, i + 1);
        COMPF(xa, xb);
        if (i + 2 < 16) LOADF(xa, xb, i + 2);
        COMPF(ya, yb);
    }

    #pragma unroll
    for (int ct = 0; ct < 4; ++ct) {
        const int nc = (nf0 + ct) * 16 + col;
        float bv = bias[nc];
        #pragma unroll
        for (int mt = 0; mt < 4; ++mt) {
            ushort_t* base = C + (size_t)((mf0 + mt) * 16 + (lane >> 4) * 4) * 512 + nc;
            #pragma unroll
            for (int r = 0; r < 4; ++r)
                base[(size_t)r * 512] = f2bf(acc[mt][ct][r] + bv);
        }
    }
}

// ---------------------------------------------------------------------------
// Batched logits GEMM: packed split-1, W2D, XCD-swizzled, PERM nontemporal.
// ---------------------------------------------------------------------------
__global__ __launch_bounds__(256)
void logits_k(const ushort_t* __restrict__ AH, const ushort_t* __restrict__ BH,
              const float* __restrict__ bias, float* __restrict__ C)
{
    constexpr int aFS = 16 * 512;
    constexpr long long ldc = (long long)Tt * Vv, ldc2 = Vv;
    const int nwg = 79 * 20;
    const int orig = blockIdx.x;
    const int xcd = orig & 7, idx = orig >> 3;
    const int q = nwg >> 3, r = nwg & 7;
    const int lin = (xcd < r ? xcd * (q + 1) : r * (q + 1) + (xcd - r) * q) + idx;
    const int bx = lin / 20, by = lin - bx * 20;

    const int wv = threadIdx.x >> 6, lane = threadIdx.x & 63;
    const int nf0 = (bx * 2 + (wv & 1)) * 4;
    const int mf0 = by * 8 + (wv >> 1) * 4;
    if (nf0 >= 625) return;
    const int col = lane & 15;
    const int lofs = lane * 8;

    const ushort_t *paH[4], *pbH[4];
    #pragma unroll
    for (int mt = 0; mt < 4; ++mt) paH[mt] = AH + (size_t)(mf0 + mt) * aFS + lofs;
    #pragma unroll
    for (int ct = 0; ct < 4; ++ct) {
        int nf = nf0 + ct; if (nf > 624) nf = 624;
        pbH[ct] = BH + (size_t)nf * aFS + lofs;
    }

    f32x4 acc[4][4];
    #pragma unroll
    for (int mt = 0; mt < 4; ++mt)
        #pragma unroll
        for (int ct = 0; ct < 4; ++ct) acc[mt][ct] = (f32x4){0.f, 0.f, 0.f, 0.f};

    auto LOADF = [&](bf16x8 (&A0)[4], bf16x8 (&B0)[4], int i) {
        size_t o = (size_t)i * 512;
        #pragma unroll
        for (int mt = 0; mt < 4; ++mt) A0[mt] = *(const bf16x8*)(paH[mt] + o);
        #pragma unroll
        for (int ct = 0; ct < 4; ++ct) B0[ct] = *(const bf16x8*)(pbH[ct] + o);
    };
    auto COMPF = [&](bf16x8 (&A0)[4], bf16x8 (&B0)[4]) {
        #pragma unroll
        for (int mt = 0; mt < 4; ++mt)
            #pragma unroll
            for (int ct = 0; ct < 4; ++ct)
                acc[mt][ct] = __builtin_amdgcn_mfma_f32_16x16x32_bf16(A0[mt], B0[ct], acc[mt][ct], 0, 0, 0);
    };

    bf16x8 xa[4], xb[4], ya[4], yb[4];
    LOADF(xa, xb, 0);
    for (int i = 0; i < 16; i += 2) {
        LOADF(ya, yb, i + 1);
        COMPF(xa, xb);
        if (i + 2 < 16) LOADF(xa, xb, i + 2);
        COMPF(ya, yb);
    }

    // epilogue: per-mt hoisted row base (row&127 = (fr&7)*16 + quad, row>>7 = fr>>3)
    #pragma unroll
    for (int mt = 0; mt < 4; ++mt) {
        const int fr = mf0 + mt;
        float* base = C + (size_t)((fr & 7) * 16 + (lane >> 4) * 4) * ldc
                        + (size_t)(fr >> 3) * ldc2;
        #pragma unroll
        for (int ct = 0; ct < 4; ++ct) {
            const int nc = (nf0 + ct) * 16 + col;
            if (nc >= Vv) continue;
            float bv = bias[nc];
            #pragma unroll
            for (int r = 0; r < 4; ++r)
                __builtin_nontemporal_store(acc[mt][ct][r] + bv, base + (size_t)r * ldc + nc);
        }
    }
}

// ---------------------------------------------------------------------------
// MEGA setup kernel: all weight conversions + img conversion + featmean + bcomb
// ---------------------------------------------------------------------------
DEV void convT_body(int tid, const float* __restrict__ W, int N, int KSr,
                    ushort_t* __restrict__ PH, int KSfull, int ksOfs, int nfOfs)
{
    int lane = tid & 63;
    int rest = tid >> 6;
    int ks = rest % KSr;
    int nf = rest / KSr;
    const float* src = W + (size_t)(ks * 32 + ((lane >> 4) & 3) * 8) * N
                         + nf * 16 + (lane & 15);
    size_t dbase = (((size_t)(nf + nfOfs) * KSfull + ks + ksOfs) * 64 + lane) * 8;
    #pragma unroll
    for (int jj = 0; jj < 8; ++jj)
        PH[dbase + jj] = f2bf(src[(size_t)jj * N]);
}

__global__ __launch_bounds__(256)
void setup_mega_k(const float* __restrict__ W_out, const float* __restrict__ W_ih,
                  const float* __restrict__ W_hh, const float* __restrict__ W_ad,
                  const float* __restrict__ W_gate, const float* __restrict__ W_ae,
                  ushort_t* __restrict__ WoutPk, ushort_t* __restrict__ WgPk,
                  ushort_t* __restrict__ WdgPk, ushort_t* __restrict__ WaePk,
                  const float* __restrict__ img, ushort_t* __restrict__ linH,
                  ushort_t* __restrict__ pkH, float* __restrict__ fm,
                  const float* __restrict__ bih, const float* __restrict__ bhh,
                  float* __restrict__ bc)
{
    const int blk = blockIdx.x, tid = threadIdx.x;
    if (blk < 2500) {
        convT_body((blk - 0) * 256 + tid, W_out, Vv, 16, WoutPk, 16, 0, 0);
    } else if (blk < 3268) {
        convT_body((blk - 2500) * 256 + tid, W_ih, 2048, 24, WgPk, 40, 0, 0);
    } else if (blk < 3780) {
        convT_body((blk - 3268) * 256 + tid, W_hh, 2048, 16, WgPk, 40, 24, 0);
    } else if (blk < 3908) {
        convT_body((blk - 3780) * 256 + tid, W_ad, Hh, 16, WdgPk, 16, 0, 0);
    } else if (blk < 4036) {
        convT_body((blk - 3908) * 256 + tid, W_gate, Hh, 16, WdgPk, 16, 0, 32);
    } else if (blk < 4164) {
        convT_body((blk - 4036) * 256 + tid, W_ae, Hh, 16, WaePk, 16, 0, 0);
    } else if (blk < 10436) {
        if (!linH) return;
        int ltid = (blk - 4164) * 256 + tid;
        int lane = ltid & 63;
        int rest = ltid >> 6;
        int ks = rest & 15, rf = rest >> 4;
        int r = rf * 16 + (lane & 15);
        int k = ks * 32 + ((lane >> 4) & 3) * 8;
        const float* src = img + (size_t)r * 512 + k;
        ushort_t* ld = linH + (size_t)r * 512 + k;
        size_t pidx = (((size_t)rf * 16 + ks) * 64 + lane) * 8;
        #pragma unroll
        for (int jj = 0; jj < 8; ++jj) {
            ushort_t h = f2bf(src[jj]);
            ld[jj] = h;
            pkH[pidx + jj] = h;
        }
    } else {
        int b = blk - 10436;
        if (b < 8) {
            int i = b * 256 + tid;
            bc[i] = bih[i] + bhh[i];
        }
        const float* base = img + (size_t)b * Ll * ENCe;
        for (int e = tid; e < ENCe; e += 256) {
            float s = 0.f;
            for (int l = 0; l < Ll; ++l) s += base[l * ENCe + e];
            fm[b * ENCe + e] = s * (1.f / (float)Ll);
        }
    }
}

// fallback: fp32 -> bf16 hi (linear only)
__global__ void convbf_k(const float* __restrict__ src, ushort_t* __restrict__ dst,
                         long long n)
{
    long long i = (long long)(blockIdx.x * 256 + threadIdx.x) * 4;
    long long stride = (long long)gridDim.x * 1024;
    for (; i + 3 < n; i += stride) {
        float4 v = *(const float4*)&src[i];
        dst[i + 0] = f2bf(v.x); dst[i + 1] = f2bf(v.y);
        dst[i + 2] = f2bf(v.z); dst[i + 3] = f2bf(v.w);
    }
}

// ---------------------------------------------------------------------------
// Per-step loop kernels
// ---------------------------------------------------------------------------
struct LP {
    const ushort_t *WdgH, *WgH;
    const float    *b_ad, *b_gate, *bcomb;
    float          *dgb, *cbuf;
    ushort_t       *xhH, *xhL, *hsH;
};

// dg = [h@W_ad + b_ad | sigmoid(h@W_gate + b_gate)]  (256 blocks, 2-wave K-split)
// split-2: Ahi*Bhi + Alo*Bhi (h lo kept -> alphas path protected)
__global__ __launch_bounds__(256)
void ph_dg_k(LP P)
{
    __shared__ f32x4 part[2][64];
    const int beta = blockIdx.x;
    const int tid = threadIdx.x, wv = tid >> 6, lane = tid & 63;
    const int bx = beta >> 3, mf = beta & 7;
    const int nf = bx * 2 + (wv & 1), kh = wv >> 1;
    const int lofs = lane * 8;

    const ushort_t* paH = P.xhH + ((size_t)mf * 40 + 24 + kh * 8) * 512 + lofs;
    const ushort_t* paL = P.xhL + ((size_t)mf * 40 + 24 + kh * 8) * 512 + lofs;
    const ushort_t* pbH = P.WdgH + ((size_t)nf * 16 + kh * 8) * 512 + lofs;

    f32x4 acc = (f32x4){0.f, 0.f, 0.f, 0.f};
    #pragma unroll
    for (int i = 0; i < 8; ++i) {
        size_t o = (size_t)i * 512;
        bf16x8 A0 = *(const bf16x8*)(paH + o);
        bf16x8 A1 = *(const bf16x8*)(paL + o);
        bf16x8 B0 = *(const bf16x8*)(pbH + o);
        acc = __builtin_amdgcn_mfma_f32_16x16x32_bf16(A0, B0, acc, 0, 0, 0);
        acc = __builtin_amdgcn_mfma_f32_16x16x32_bf16(A1, B0, acc, 0, 0, 0);
    }

    if (kh == 1) part[wv & 1][lane] = acc;
    __syncthreads();
    if (kh == 0) {
        acc += part[wv & 1][lane];
        int n = nf * 16 + (lane & 15);
        float bv = (n < 512) ? P.b_ad[n] : P.b_gate[n - 512];
        #pragma unroll
        for (int r = 0; r < 4; ++r) {
            int row = mf * 16 + (lane >> 4) * 4 + r;
            float v = acc[r] + bv;
            if (n >= 512) v = sigm_f(v);
            P.dgb[row * 1024 + n] = v;
        }
    }
}

// Fused attention (128 blocks x 512 threads), vectorized loads
template<bool IMGBF>
__global__ __launch_bounds__(512)
void attn_fused_k(const ushort_t* __restrict__ enc, const float* __restrict__ dgb,
                  const float* __restrict__ v_att,
                  const ushort_t* __restrict__ img_bf, const float* __restrict__ img_f,
                  const float* __restrict__ emb, const int* __restrict__ captions,
                  float* __restrict__ alphas, long long alpha_stride,
                  ushort_t* __restrict__ xhi, int t)
{
    int b = blockIdx.x, tid = threadIdx.x;
    int wv = tid >> 6, ln = tid & 63;
    __shared__ float es[Ll], red[8];
    __shared__ float ctxp[8][ENCe];   // 16 KB

    float dp_r[8], va_r[8];
    {
        const float4* dptr = (const float4*)(dgb + b * 1024 + ln * 8);
        const float4* vptr = (const float4*)(v_att + ln * 8);
        float4 d0 = dptr[0], d1 = dptr[1];
        float4 v0 = vptr[0], v1 = vptr[1];
        dp_r[0] = d0.x; dp_r[1] = d0.y; dp_r[2] = d0.z; dp_r[3] = d0.w;
        dp_r[4] = d1.x; dp_r[5] = d1.y; dp_r[6] = d1.z; dp_r[7] = d1.w;
        va_r[0] = v0.x; va_r[1] = v0.y; va_r[2] = v0.z; va_r[3] = v0.w;
        va_r[4] = v1.x; va_r[5] = v1.y; va_r[6] = v1.z; va_r[7] = v1.w;
    }

    const ushort_t* ep = enc + (size_t)b * Ll * Hh;
    for (int l = wv; l < Ll; l += 8) {
        bf16x8 v8 = *(const bf16x8*)(ep + (size_t)l * Hh + ln * 8);
        float s = 0.f;
        #pragma unroll
        for (int j = 0; j < 8; ++j)
            s += tanh_f(bf2f((ushort_t)v8[j]) + dp_r[j]) * va_r[j];
        #pragma unroll
        for (int o = 32; o; o >>= 1) s += __shfl_xor(s, o);
        if (ln == 0) es[l] = s;
    }
    __syncthreads();

    float v = (tid < Ll) ? es[tid] : -1e30f;
    float m = v;
    #pragma unroll
    for (int o = 32; o; o >>= 1) m = fmaxf(m, __shfl_xor(m, o));
    if (ln == 0) red[wv] = m;
    __syncthreads();
    m = red[0];
    #pragma unroll
    for (int i = 1; i < 8; ++i) m = fmaxf(m, red[i]);
    __syncthreads();
    float p = (tid < Ll) ? __expf(v - m) : 0.f;
    float s = p;
    #pragma unroll
    for (int o = 32; o; o >>= 1) s += __shfl_xor(s, o);
    if (ln == 0) red[wv] = s;
    __syncthreads();
    s = 0.f;
    #pragma unroll
    for (int i = 0; i < 8; ++i) s += red[i];
    float inv = 1.f / s;
    if (tid < Ll) {
        float a = p * inv;
        es[tid] = a;
        alphas[(size_t)b * alpha_stride + tid] = a;
    }
    if (tid < Ee) {
        float xv = emb[(size_t)captions[b * Tt + t] * Ee + tid];
        store_xh1(xhi, b, tid, xv);
    }
    __syncthreads();

    // ctx: 8 waves; thread covers 8 e-cols (16B loads); l-ranges 25x4 + 24x4
    {
        const int g = wv, tl = ln;
        const int l0 = (g < 4) ? g * 25 : 100 + (g - 4) * 24;
        const int nl = (g < 4) ? 25 : 24;
        float a[8] = {};
        if (IMGBF) {
            const ushort_t* ib = img_bf + (size_t)b * Ll * ENCe + tl * 8;
            for (int i = 0; i < nl; ++i) {
                float al = es[l0 + i];
                bf16x8 u = *(const bf16x8*)(ib + (size_t)(l0 + i) * ENCe);
                #pragma unroll
                for (int j = 0; j < 8; ++j)
                    a[j] = fmaf(al, bf2f((ushort_t)u[j]), a[j]);
            }
        } else {
            const float* ib = img_f + (size_t)b * Ll * ENCe + tl * 8;
            for (int i = 0; i < nl; ++i) {
                float al = es[l0 + i];
                float4 u0 = *(const float4*)(ib + (size_t)(l0 + i) * ENCe);
                float4 u1 = *(const float4*)(ib + (size_t)(l0 + i) * ENCe + 4);
                a[0] = fmaf(al, u0.x, a[0]); a[1] = fmaf(al, u0.y, a[1]);
                a[2] = fmaf(al, u0.z, a[2]); a[3] = fmaf(al, u0.w, a[3]);
                a[4] = fmaf(al, u1.x, a[4]); a[5] = fmaf(al, u1.y, a[5]);
                a[6] = fmaf(al, u1.z, a[6]); a[7] = fmaf(al, u1.w, a[7]);
            }
        }
        #pragma unroll
        for (int j = 0; j < 8; j += 4) {
            f32x4 pv = (f32x4){a[j], a[j + 1], a[j + 2], a[j + 3]};
            *(f32x4*)&ctxp[g][tl * 8 + j] = pv;
        }
    }
    __syncthreads();

    {
        float cv = 0.f;
        #pragma unroll
        for (int g = 0; g < 8; ++g) cv += ctxp[g][tid];
        float xv = cv * dgb[b * 1024 + 512 + tid];
        store_xh1(xhi, b, 256 + tid, xv);
    }
}

// gates GEMM (4-wave K-split, split-1) + fused LSTM, parallel epilogue
__global__ __launch_bounds__(256)
void ph_gates_k(LP P, int t)
{
    __shared__ f32x4 part[4][4][64];
    const int beta = blockIdx.x;
    const int tid = threadIdx.x, wv = tid >> 6, lane = tid & 63;
    const int jf = beta & 31, mq = beta >> 5;
    const int ks0 = wv * 10, lofs = lane * 8;
    constexpr int FS = 40 * 512;

    const ushort_t* paH = P.xhH + ((size_t)mq * 40 + ks0) * 512 + lofs;
    const ushort_t *pbH[4];
    #pragma unroll
    for (int g = 0; g < 4; ++g)
        pbH[g] = P.WgH + (size_t)(g * 32 + jf) * FS + (size_t)ks0 * 512 + lofs;

    f32x4 acc[4];
    #pragma unroll
    for (int g = 0; g < 4; ++g) acc[g] = (f32x4){0.f, 0.f, 0.f, 0.f};

    auto LOADF = [&](bf16x8& A, bf16x8 (&B)[4], int i) {
        size_t o = (size_t)i * 512;
        A = *(const bf16x8*)(paH + o);
        #pragma unroll
        for (int g = 0; g < 4; ++g) B[g] = *(const bf16x8*)(pbH[g] + o);
    };
    auto COMPF = [&](bf16x8& A, bf16x8 (&B)[4]) {
        #pragma unroll
        for (int g = 0; g < 4; ++g)
            acc[g] = __builtin_amdgcn_mfma_f32_16x16x32_bf16(A, B[g], acc[g], 0, 0, 0);
    };

    bf16x8 xA, xB[4], yA, yB[4];
    LOADF(xA, xB, 0);
    for (int i = 0; i < 10; i += 2) {
        LOADF(yA, yB, i + 1);
        COMPF(xA, xB);
        if (i + 2 < 10) LOADF(xA, xB, i + 2);
        COMPF(yA, yB);
    }

    #pragma unroll
    for (int g = 0; g < 4; ++g) part[wv][g][lane] = acc[g];
    __syncthreads();

    const int jl = tid & 15, bl = tid >> 4;
    const int lane2 = (bl >> 2) * 16 + jl, r2 = bl & 3;
    float g4[4];
    #pragma unroll
    for (int g = 0; g < 4; ++g)
        g4[g] = part[0][g][lane2][r2] + part[1][g][lane2][r2]
              + part[2][g][lane2][r2] + part[3][g][lane2][r2];

    const int j = jf * 16 + jl;
    const int b = mq * 16 + bl;
    float ig = sigm_f(g4[0] + P.bcomb[j]);
    float fg = sigm_f(g4[1] + P.bcomb[512 + j]);
    float gg = tanh_f(g4[2] + P.bcomb[1024 + j]);
    float og = sigm_f(g4[3] + P.bcomb[1536 + j]);
    float cn = fg * P.cbuf[b * 512 + j] + ig * gg;
    P.cbuf[b * 512 + j] = cn;
    float hv = og * tanh_f(cn);
    store_xh2(P.xhH, P.xhL, b, 768 + j, hv);   // hi+lo (dg consumes lo)
    size_t hidx = (((size_t)(t * 8 + (b >> 4)) * 16 + (j >> 5)) * 64
                   + ((j >> 3) & 3) * 16 + (b & 15)) * 8 + (j & 7);
    P.hsH[hidx] = f2bf(hv);
}

// ---------------------------------------------------------------------------
extern "C" void kernel_launch(void* const* d_in, const int* in_sizes, int n_in,
                              void* d_out, int out_size, void* d_ws, size_t ws_size,
                              hipStream_t stream)
{
    const float* img    = (const float*)d_in[0];
    const float* W_h    = (const float*)d_in[1];
    const float* b_h    = (const float*)d_in[2];
    const float* W_c    = (const float*)d_in[3];
    const float* b_c    = (const float*)d_in[4];
    const float* W_gate = (const float*)d_in[5];
    const float* b_gate = (const float*)d_in[6];
    const float* emb    = (const float*)d_in[7];
    const float* W_ae   = (const float*)d_in[8];
    const float* b_ae   = (const float*)d_in[9];
    const float* W_ad   = (const float*)d_in[10];
    const float* b_ad   = (const float*)d_in[11];
    const float* v_att  = (const float*)d_in[12];
    const float* W_ih   = (const float*)d_in[14];
    const float* b_ih   = (const float*)d_in[15];
    const float* W_hh   = (const float*)d_in[16];
    const float* b_hh   = (const float*)d_in[17];
    const float* W_out  = (const float*)d_in[18];
    const float* b_out  = (const float*)d_in[19];
    const int* captions = (const int*)d_in[20];

    float* out    = (float*)d_out;                       // [B,T,V]
    float* alphas = out + (size_t)Bb * Tt * Vv;          // [B,T,L]

    // ---- workspace allocator (256B aligned) ----
    char* p = (char*)d_ws;
    auto alloc = [&](size_t bytes) -> char* {
        char* r = p; p += (bytes + 255) & ~(size_t)255; return r;
    };
    const size_t szEnc   = (size_t)Bb * Ll * Hh * 2;
    const size_t szWout  = (size_t)625 * 16 * 512 * 2;
    const size_t szWg    = (size_t)128 * 40 * 512 * 2;
    const size_t szWdg   = (size_t)64 * 16 * 512 * 2;
    const size_t szWae   = (size_t)32 * 16 * 512 * 2;
    const size_t szXh    = (size_t)8 * 40 * 512 * 2;
    const size_t szHseq  = (size_t)160 * 16 * 512 * 2;
    const size_t szImg   = (size_t)Bb * Ll * ENCe * 2;

    ushort_t* enc_hi  = (ushort_t*)alloc(szEnc);
    ushort_t* WoutPkH = (ushort_t*)alloc(szWout);
    ushort_t* WgPkH   = (ushort_t*)alloc(szWg);
    ushort_t* WdgPkH  = (ushort_t*)alloc(szWdg);
    ushort_t* WaePkH  = (ushort_t*)alloc(szWae);
    ushort_t* xhPkH   = (ushort_t*)alloc(szXh);
    ushort_t* xhPkL   = (ushort_t*)alloc(szXh);
    ushort_t* hseqPkH = (ushort_t*)alloc(szHseq);
    float*    cbuf    = (float*)alloc((size_t)Bb * Hh * 4);
    float*    dgb     = (float*)alloc((size_t)Bb * 1024 * 4);
    float*    fm      = (float*)alloc((size_t)Bb * ENCe * 4);
    float*    bcomb   = (float*)alloc(4 * Hh * 4);

    auto tryAlloc = [&](size_t bytes) -> char* {
        size_t used = (size_t)(p - (char*)d_ws);
        size_t rounded = (bytes + 255) & ~(size_t)255;
        if (used + rounded > ws_size) return nullptr;
        return alloc(bytes);
    };
    ushort_t* imgLin = (ushort_t*)tryAlloc(szImg);
    ushort_t* imgPk  = (ushort_t*)tryAlloc(szImg);

    dim3 blk(256);

    // ---- setup: ONE mega kernel (conversions + featmean + bcomb) ----
    setup_mega_k<<<10564, blk, 0, stream>>>(
        W_out, W_ih, W_hh, W_ad, W_gate, W_ae,
        WoutPkH, WgPkH, WdgPkH, WaePkH,
        img, imgLin, imgPk, fm, b_ih, b_hh, bcomb);

    // enc_proj (standalone MFMA kernel) + h0/c0 (separate dispatches —
    // merged version regressed: co-compiled branches coupled reg budgets)
    if (imgPk && imgLin) {
        enc_k<<<784, blk, 0, stream>>>(imgPk, WaePkH, b_ae, enc_hi);
        h0c0_k<<<dim3(16, 4), blk, 0, stream>>>(fm, W_h, b_h, W_c, b_c,
                                                xhPkH, xhPkL, cbuf);
    } else {
        h0c0_k<<<dim3(16, 4), blk, 0, stream>>>(fm, W_h, b_h, W_c, b_c,
                                                xhPkH, xhPkL, cbuf);
        if (imgLin) convbf_k<<<2048, blk, 0, stream>>>(img, imgLin, (long long)Bb * Ll * ENCe);
        gemm_k<64, 4, 4, 0, 1><<<dim3(Hh / 64, (Bb * Ll) / 64), blk, 0, stream>>>(
            img, ENCe, W_ae, Hh, b_ae, enc_hi, Hh, Bb * Ll, Hh, ENCe);
    }

    // ---- 20-step loop: 3 dispatches per step ----
    LP P;
    P.WdgH = WdgPkH; P.WgH = WgPkH;
    P.b_ad = b_ad; P.b_gate = b_gate; P.bcomb = bcomb;
    P.dgb = dgb; P.cbuf = cbuf;
    P.xhH = xhPkH; P.xhL = xhPkL; P.hsH = hseqPkH;

    for (int t = 0; t < Tt; ++t) {
        ph_dg_k<<<256, blk, 0, stream>>>(P);
        if (imgLin)
            attn_fused_k<true ><<<Bb, dim3(512), 0, stream>>>(
                enc_hi, dgb, v_att, imgLin, nullptr, emb, captions,
                alphas + (size_t)t * Ll, (long long)Tt * Ll, xhPkH, t);
        else
            attn_fused_k<false><<<Bb, dim3(512), 0, stream>>>(
                enc_hi, dgb, v_att, nullptr, img, emb, captions,
                alphas + (size_t)t * Ll, (long long)Tt * Ll, xhPkH, t);
        ph_gates_k<<<256, blk, 0, stream>>>(P, t);
    }

    // ---- batched logits (split-1) -> out[b][t][v] ----
    logits_k<<<79 * 20, blk, 0, stream>>>(hseqPkH, WoutPkH, b_out, out);
}

// Round 17
// 935.500 us; speedup vs baseline: 1.0255x; 1.0255x over previous
//
#include <hip/hip_runtime.h>
#include <math.h>

typedef unsigned short ushort_t;
typedef __attribute__((ext_vector_type(8))) short bf16x8;
typedef __attribute__((ext_vector_type(4))) short bf16x4;
typedef __attribute__((ext_vector_type(4))) float f32x4;

constexpr int Bb  = 128;
constexpr int Ll  = 196;
constexpr int ENCe= 512;
constexpr int Hh  = 512;
constexpr int Ee  = 256;
constexpr int Vv  = 10000;
constexpr int Tt  = 20;

#define DEV __device__ __forceinline__

DEV float sigm_f(float x) { return 1.f / (1.f + __expf(-x)); }
DEV float tanh_f(float x) {
    x = fminf(fmaxf(x, -15.f), 15.f);
    float e = __expf(2.f * x);
    return (e - 1.f) / (e + 1.f);
}
DEV ushort_t f2bf(float v) {
    unsigned u = __float_as_uint(v);
    return (ushort_t)((u + 0x7FFFu + ((u >> 16) & 1u)) >> 16);
}
DEV float bf2f(ushort_t h) { return __uint_as_float(((unsigned)h) << 16); }

// Packed-fragment layout for a logical [R][K] bf16 matrix:
//   (r,k) -> ((r>>4)*KS + (k>>5))*512 + (((k>>3)&3)*16 + (r&15))*8 + (k&7)
DEV void store_xh(ushort_t* __restrict__ H, ushort_t* __restrict__ L,
                  int b, int k, float v)
{
    size_t idx = (((size_t)(b >> 4) * 40 + (k >> 5)) * 64
                  + ((k >> 3) & 3) * 16 + (b & 15)) * 8 + (k & 7);
    ushort_t hb = f2bf(v);
    H[idx] = hb;
    L[idx] = f2bf(v - bf2f(hb));
}

// ---------------------------------------------------------------------------
// fp32 tiled GEMM (enc_proj fallback only). OUTBF emits bf16.
// ---------------------------------------------------------------------------
template<int BN, int TM, int TN, int ACT1, int OUTBF>
__global__ __launch_bounds__(256)
void gemm_k(const float* __restrict__ A, int lda,
            const float* __restrict__ Wk, int ldw,
            const float* __restrict__ bias,
            void* __restrict__ Cv, long long ldc,
            int M, int N, int K)
{
    constexpr int BM = 64, BK = 16;
    constexpr int TX = BN / TN, TY = BM / TM;
    static_assert(TX * TY == 256, "bad tile config");
    __shared__ float As[BK][BM];
    __shared__ float Ws[BK][BN];

    const int tid = threadIdx.x;
    const int tx = tid % TX, ty = tid / TX;
    const int nb = blockIdx.x * BN, mb = blockIdx.y * BM;

    float acc[TM][TN] = {};
    const int am = tid >> 2;
    const int ak = (tid & 3) * 4;
    const int wn = tid % BN;
    const int wk0 = tid / BN;
    constexpr int WKSTEP = 256 / BN;

    for (int k0 = 0; k0 < K; k0 += BK) {
        float4 av = *(const float4*)&A[(size_t)(mb + am) * lda + k0 + ak];
        As[ak + 0][am] = av.x;
        As[ak + 1][am] = av.y;
        As[ak + 2][am] = av.z;
        As[ak + 3][am] = av.w;
        #pragma unroll
        for (int i = 0; i < BK / WKSTEP; ++i) {
            int kw = wk0 + i * WKSTEP;
            Ws[kw][wn] = (nb + wn < N) ? Wk[(size_t)(k0 + kw) * ldw + nb + wn] : 0.f;
        }
        __syncthreads();
        #pragma unroll
        for (int k = 0; k < BK; ++k) {
            float a[TM], w[TN];
            #pragma unroll
            for (int i = 0; i < TM; ++i) a[i] = As[k][ty * TM + i];
            #pragma unroll
            for (int j = 0; j < TN; ++j) w[j] = Ws[k][tx * TN + j];
            #pragma unroll
            for (int i = 0; i < TM; ++i)
                #pragma unroll
                for (int j = 0; j < TN; ++j)
                    acc[i][j] = fmaf(a[i], w[j], acc[i][j]);
        }
        __syncthreads();
    }

    #pragma unroll
    for (int i = 0; i < TM; ++i) {
        int m = mb + ty * TM + i;
        #pragma unroll
        for (int j = 0; j < TN; ++j) {
            int n = nb + tx * TN + j;
            if (n < N) {
                float v = acc[i][j];
                if (bias) v += bias[n];
                if (ACT1 == 1) v = tanh_f(v);
                if (OUTBF) ((ushort_t*)Cv)[(size_t)m * ldc + n] = f2bf(v);
                else       ((float*)Cv)[(size_t)m * ldc + n] = v;
            }
        }
    }
}

// ---------------------------------------------------------------------------
// Merged h0/c0 GEMM: grid (16, 4). by&1 = m-block; by>>1 selects:
//   0: xh[m][768+n] = tanh(fm@W_h + b_h)  (packed store)
//   1: cbuf[m][n]   = tanh(fm@W_c + b_c)
// ---------------------------------------------------------------------------
__global__ __launch_bounds__(256)
void h0c0_k(const float* __restrict__ fm,
            const float* __restrict__ W_h, const float* __restrict__ b_h,
            const float* __restrict__ W_c, const float* __restrict__ b_c,
            ushort_t* __restrict__ xhH, ushort_t* __restrict__ xhL,
            float* __restrict__ cbuf)
{
    constexpr int BM = 64, BK = 16, BN = 32, TM = 2, TN = 4;
    constexpr int TX = BN / TN;
    __shared__ float As[BK][BM];
    __shared__ float Ws[BK][BN];

    const int sel = blockIdx.y >> 1;
    const float* Wk   = sel ? W_c : W_h;
    const float* bias = sel ? b_c : b_h;

    const int tid = threadIdx.x;
    const int tx = tid % TX, ty = tid / TX;
    const int nb = blockIdx.x * BN, mb = (blockIdx.y & 1) * BM;

    float acc[TM][TN] = {};
    const int am = tid >> 2;
    const int ak = (tid & 3) * 4;
    const int wn = tid % BN;
    const int wk0 = tid / BN;
    constexpr int WKSTEP = 256 / BN;

    for (int k0 = 0; k0 < ENCe; k0 += BK) {
        float4 av = *(const float4*)&fm[(size_t)(mb + am) * ENCe + k0 + ak];
        As[ak + 0][am] = av.x;
        As[ak + 1][am] = av.y;
        As[ak + 2][am] = av.z;
        As[ak + 3][am] = av.w;
        #pragma unroll
        for (int i = 0; i < BK / WKSTEP; ++i) {
            int kw = wk0 + i * WKSTEP;
            Ws[kw][wn] = Wk[(size_t)(k0 + kw) * Hh + nb + wn];
        }
        __syncthreads();
        #pragma unroll
        for (int k = 0; k < BK; ++k) {
            float a[TM], w[TN];
            #pragma unroll
            for (int i = 0; i < TM; ++i) a[i] = As[k][ty * TM + i];
            #pragma unroll
            for (int j = 0; j < TN; ++j) w[j] = Ws[k][tx * TN + j];
            #pragma unroll
            for (int i = 0; i < TM; ++i)
                #pragma unroll
                for (int j = 0; j < TN; ++j)
                    acc[i][j] = fmaf(a[i], w[j], acc[i][j]);
        }
        __syncthreads();
    }

    #pragma unroll
    for (int i = 0; i < TM; ++i) {
        int m = mb + ty * TM + i;
        #pragma unroll
        for (int j = 0; j < TN; ++j) {
            int n = nb + tx * TN + j;
            float v = tanh_f(acc[i][j] + bias[n]);
            if (sel) cbuf[(size_t)m * Hh + n] = v;
            else     store_xh(xhH, xhL, m, 768 + n, v);
        }
    }
}

// ---------------------------------------------------------------------------
// Packed-fragment MFMA GEMM with register double-buffer prefetch.
// SPLIT: 1 = Ahi*Bhi; 2 = +Alo*Bhi.
// PERM: C row m = t*128+b -> out[b][t][:] (scalar nontemporal stores,
//       ct-outer epilogue order — measured best: 62us / 112MB write).
// XSWZ: 1D grid, bijective XCD swizzle.
// ---------------------------------------------------------------------------
template<int MT, int NT, int ACT1, int ACT2, int SPLIT, bool OUTBF, bool PERM,
         bool XSWZ, bool NMINOR, bool W2D>
__global__ __launch_bounds__(256)
void mgemm_pk(const ushort_t* __restrict__ AH, const ushort_t* __restrict__ AL, int aFS,
              const ushort_t* __restrict__ BH, const ushort_t* __restrict__ BL, int bFS,
              const float* __restrict__ bias, const float* __restrict__ bias2, int N1,
              void* __restrict__ Cv, long long ldc, long long ldc2,
              int Nfrags, int Ntot, int nsteps, int bdiv)
{
    int bx, by;
    if (XSWZ) {
        int nwg = gridDim.x, orig = blockIdx.x;
        int xcd = orig & 7, idx = orig >> 3;
        int q = nwg >> 3, r = nwg & 7;
        int lin = (xcd < r ? xcd * (q + 1) : r * (q + 1) + (xcd - r) * q) + idx;
        int l1 = lin / bdiv, l2 = lin - l1 * bdiv;
        bx = NMINOR ? l2 : l1;
        by = NMINOR ? l1 : l2;
    } else { bx = blockIdx.x; by = blockIdx.y; }

    const int wv = threadIdx.x >> 6, lane = threadIdx.x & 63;
    int nf0, mf0;
    if (W2D) {
        nf0 = (bx * 2 + (wv & 1)) * NT;
        mf0 = by * (2 * MT) + (wv >> 1) * MT;
    } else {
        nf0 = (bx * 4 + wv) * NT;
        mf0 = by * MT;
    }
    if (nf0 >= Nfrags) return;
    const int col = lane & 15;
    const int lofs = lane * 8;

    const ushort_t *paH[MT], *paL[MT], *pbH[NT];
    #pragma unroll
    for (int mt = 0; mt < MT; ++mt) {
        paH[mt] = AH + (size_t)(mf0 + mt) * aFS + lofs;
        paL[mt] = (SPLIT >= 2) ? (AL + (size_t)(mf0 + mt) * aFS + lofs) : paH[mt];
    }
    #pragma unroll
    for (int ct = 0; ct < NT; ++ct) {
        int nf = nf0 + ct; if (nf > Nfrags - 1) nf = Nfrags - 1;
        pbH[ct] = BH + (size_t)nf * bFS + lofs;
    }

    f32x4 acc[MT][NT];
    #pragma unroll
    for (int mt = 0; mt < MT; ++mt)
        #pragma unroll
        for (int ct = 0; ct < NT; ++ct) acc[mt][ct] = (f32x4){0.f, 0.f, 0.f, 0.f};

    auto LOADF = [&](bf16x8 (&A0)[MT], bf16x8 (&A1)[MT], bf16x8 (&B0)[NT], int i) {
        size_t o = (size_t)i * 512;
        #pragma unroll
        for (int mt = 0; mt < MT; ++mt) {
            A0[mt] = *(const bf16x8*)(paH[mt] + o);
            if (SPLIT >= 2) A1[mt] = *(const bf16x8*)(paL[mt] + o);
        }
        #pragma unroll
        for (int ct = 0; ct < NT; ++ct)
            B0[ct] = *(const bf16x8*)(pbH[ct] + o);
    };
    auto COMPF = [&](bf16x8 (&A0)[MT], bf16x8 (&A1)[MT], bf16x8 (&B0)[NT]) {
        #pragma unroll
        for (int mt = 0; mt < MT; ++mt)
            #pragma unroll
            for (int ct = 0; ct < NT; ++ct) {
                acc[mt][ct] = __builtin_amdgcn_mfma_f32_16x16x32_bf16(A0[mt], B0[ct], acc[mt][ct], 0, 0, 0);
                if (SPLIT >= 2)
                    acc[mt][ct] = __builtin_amdgcn_mfma_f32_16x16x32_bf16(A1[mt], B0[ct], acc[mt][ct], 0, 0, 0);
            }
    };

    bf16x8 xa0[MT], xa1[MT], xb0[NT];
    bf16x8 ya0[MT], ya1[MT], yb0[NT];
    LOADF(xa0, xa1, xb0, 0);
    for (int i = 0; i < nsteps; i += 2) {
        LOADF(ya0, ya1, yb0, i + 1);
        COMPF(xa0, xa1, xb0);
        if (i + 2 < nsteps) LOADF(xa0, xa1, xb0, i + 2);
        COMPF(ya0, ya1, yb0);
    }

    #pragma unroll
    for (int ct = 0; ct < NT; ++ct) {
        const int nc = (nf0 + ct) * 16 + col;
        if (nc >= Ntot) continue;
        const bool ns = ((nf0 + ct) * 16 >= N1);
        float bv = ns ? (bias2 ? bias2[nc - N1] : 0.f) : (bias ? bias[nc] : 0.f);
        const int act = ns ? ACT2 : ACT1;
        #pragma unroll
        for (int mt = 0; mt < MT; ++mt)
            #pragma unroll
            for (int r = 0; r < 4; ++r) {
                int row = (mf0 + mt) * 16 + (lane >> 4) * 4 + r;
                float v = acc[mt][ct][r] + bv;
                if (act == 1)      v = tanh_f(v);
                else if (act == 2) v = sigm_f(v);
                size_t off = PERM ? ((size_t)(row & 127) * ldc + (size_t)(row >> 7) * ldc2 + nc)
                                  : ((size_t)row * ldc + nc);
                if (OUTBF)      ((ushort_t*)Cv)[off] = f2bf(v);
                else if (PERM)  __builtin_nontemporal_store(v, &((float*)Cv)[off]);
                else            ((float*)Cv)[off] = v;
            }
    }
}

// ---------------------------------------------------------------------------
// MEGA setup kernel: all weight conversions + img conversion + featmean + bcomb
// ---------------------------------------------------------------------------
DEV void convT_body(int tid, const float* __restrict__ W, int N, int KSr,
                    ushort_t* __restrict__ PH, int KSfull, int ksOfs, int nfOfs)
{
    int lane = tid & 63;
    int rest = tid >> 6;
    int ks = rest % KSr;
    int nf = rest / KSr;
    const float* src = W + (size_t)(ks * 32 + ((lane >> 4) & 3) * 8) * N
                         + nf * 16 + (lane & 15);
    size_t dbase = (((size_t)(nf + nfOfs) * KSfull + ks + ksOfs) * 64 + lane) * 8;
    #pragma unroll
    for (int jj = 0; jj < 8; ++jj)
        PH[dbase + jj] = f2bf(src[(size_t)jj * N]);
}

__global__ __launch_bounds__(256)
void setup_mega_k(const float* __restrict__ W_out, const float* __restrict__ W_ih,
                  const float* __restrict__ W_hh, const float* __restrict__ W_ad,
                  const float* __restrict__ W_gate, const float* __restrict__ W_ae,
                  ushort_t* __restrict__ WoutPk, ushort_t* __restrict__ WgPk,
                  ushort_t* __restrict__ WdgPk, ushort_t* __restrict__ WaePk,
                  const float* __restrict__ img, ushort_t* __restrict__ linH,
                  ushort_t* __restrict__ pkH, float* __restrict__ fm,
                  const float* __restrict__ bih, const float* __restrict__ bhh,
                  float* __restrict__ bc)
{
    const int blk = blockIdx.x, tid = threadIdx.x;
    if (blk < 2500) {
        convT_body((blk - 0) * 256 + tid, W_out, Vv, 16, WoutPk, 16, 0, 0);
    } else if (blk < 3268) {
        convT_body((blk - 2500) * 256 + tid, W_ih, 2048, 24, WgPk, 40, 0, 0);
    } else if (blk < 3780) {
        convT_body((blk - 3268) * 256 + tid, W_hh, 2048, 16, WgPk, 40, 24, 0);
    } else if (blk < 3908) {
        convT_body((blk - 3780) * 256 + tid, W_ad, Hh, 16, WdgPk, 16, 0, 0);
    } else if (blk < 4036) {
        convT_body((blk - 3908) * 256 + tid, W_gate, Hh, 16, WdgPk, 16, 0, 32);
    } else if (blk < 4164) {
        convT_body((blk - 4036) * 256 + tid, W_ae, Hh, 16, WaePk, 16, 0, 0);
    } else if (blk < 10436) {
        if (!linH) return;
        int ltid = (blk - 4164) * 256 + tid;
        int lane = ltid & 63;
        int rest = ltid >> 6;
        int ks = rest & 15, rf = rest >> 4;
        int r = rf * 16 + (lane & 15);
        int k = ks * 32 + ((lane >> 4) & 3) * 8;
        const float* src = img + (size_t)r * 512 + k;
        ushort_t* ld = linH + (size_t)r * 512 + k;
        size_t pidx = (((size_t)rf * 16 + ks) * 64 + lane) * 8;
        #pragma unroll
        for (int jj = 0; jj < 8; ++jj) {
            ushort_t h = f2bf(src[jj]);
            ld[jj] = h;
            pkH[pidx + jj] = h;
        }
    } else {
        int b = blk - 10436;
        if (b < 8) {
            int i = b * 256 + tid;
            bc[i] = bih[i] + bhh[i];
        }
        const float* base = img + (size_t)b * Ll * ENCe;
        for (int e = tid; e < ENCe; e += 256) {
            float s = 0.f;
            for (int l = 0; l < Ll; ++l) s += base[l * ENCe + e];
            fm[b * ENCe + e] = s * (1.f / (float)Ll);
        }
    }
}

// fallback: fp32 -> bf16 hi (linear only)
__global__ void convbf_k(const float* __restrict__ src, ushort_t* __restrict__ dst,
                         long long n)
{
    long long i = (long long)(blockIdx.x * 256 + threadIdx.x) * 4;
    long long stride = (long long)gridDim.x * 1024;
    for (; i + 3 < n; i += stride) {
        float4 v = *(const float4*)&src[i];
        dst[i + 0] = f2bf(v.x); dst[i + 1] = f2bf(v.y);
        dst[i + 2] = f2bf(v.z); dst[i + 3] = f2bf(v.w);
    }
}

// ---------------------------------------------------------------------------
// Per-step loop kernels
// ---------------------------------------------------------------------------
struct LP {
    const ushort_t *WdgH, *WgH;
    const float    *b_ad, *b_gate, *bcomb;
    float          *dgb, *cbuf;
    ushort_t       *xhH, *xhL, *hsH;
};

// dg = [h@W_ad + b_ad | sigmoid(h@W_gate + b_gate)]  (256 blocks, 2-wave K-split)
__global__ __launch_bounds__(256)
void ph_dg_k(LP P)
{
    __shared__ f32x4 part[2][64];
    const int beta = blockIdx.x;
    const int tid = threadIdx.x, wv = tid >> 6, lane = tid & 63;
    const int bx = beta >> 3, mf = beta & 7;
    const int nf = bx * 2 + (wv & 1), kh = wv >> 1;
    const int lofs = lane * 8;

    const ushort_t* paH = P.xhH + ((size_t)mf * 40 + 24 + kh * 8) * 512 + lofs;
    const ushort_t* paL = P.xhL + ((size_t)mf * 40 + 24 + kh * 8) * 512 + lofs;
    const ushort_t* pbH = P.WdgH + ((size_t)nf * 16 + kh * 8) * 512 + lofs;

    f32x4 acc = (f32x4){0.f, 0.f, 0.f, 0.f};
    #pragma unroll
    for (int i = 0; i < 8; ++i) {
        size_t o = (size_t)i * 512;
        bf16x8 A0 = *(const bf16x8*)(paH + o);
        bf16x8 A1 = *(const bf16x8*)(paL + o);
        bf16x8 B0 = *(const bf16x8*)(pbH + o);
        acc = __builtin_amdgcn_mfma_f32_16x16x32_bf16(A0, B0, acc, 0, 0, 0);
        acc = __builtin_amdgcn_mfma_f32_16x16x32_bf16(A1, B0, acc, 0, 0, 0);
    }

    if (kh == 1) part[wv & 1][lane] = acc;
    __syncthreads();
    if (kh == 0) {
        acc += part[wv & 1][lane];
        int n = nf * 16 + (lane & 15);
        float bv = (n < 512) ? P.b_ad[n] : P.b_gate[n - 512];
        #pragma unroll
        for (int r = 0; r < 4; ++r) {
            int row = mf * 16 + (lane >> 4) * 4 + r;
            float v = acc[r] + bv;
            if (n >= 512) v = sigm_f(v);
            P.dgb[row * 1024 + n] = v;
        }
    }
}

// Fused attention (128 blocks x 512 threads), vectorized loads:
//  score: per-lane dp/va in regs, one bf16x8 load per row
//  ctx:   8 waves, each thread 8 e-cols via bf16x8, LDS partial reduce
template<bool IMGBF>
__global__ __launch_bounds__(512)
void attn_fused_k(const ushort_t* __restrict__ enc, const float* __restrict__ dgb,
                  const float* __restrict__ v_att,
                  const ushort_t* __restrict__ img_bf, const float* __restrict__ img_f,
                  const float* __restrict__ emb, const int* __restrict__ captions,
                  float* __restrict__ alphas, long long alpha_stride,
                  ushort_t* __restrict__ xhi, ushort_t* __restrict__ xlo, int t)
{
    int b = blockIdx.x, tid = threadIdx.x;
    int wv = tid >> 6, ln = tid & 63;
    __shared__ float es[Ll], red[8];
    __shared__ float ctxp[8][ENCe];   // 16 KB

    float dp_r[8], va_r[8];
    {
        const float4* dptr = (const float4*)(dgb + b * 1024 + ln * 8);
        const float4* vptr = (const float4*)(v_att + ln * 8);
        float4 d0 = dptr[0], d1 = dptr[1];
        float4 v0 = vptr[0], v1 = vptr[1];
        dp_r[0] = d0.x; dp_r[1] = d0.y; dp_r[2] = d0.z; dp_r[3] = d0.w;
        dp_r[4] = d1.x; dp_r[5] = d1.y; dp_r[6] = d1.z; dp_r[7] = d1.w;
        va_r[0] = v0.x; va_r[1] = v0.y; va_r[2] = v0.z; va_r[3] = v0.w;
        va_r[4] = v1.x; va_r[5] = v1.y; va_r[6] = v1.z; va_r[7] = v1.w;
    }

    const ushort_t* ep = enc + (size_t)b * Ll * Hh;
    for (int l = wv; l < Ll; l += 8) {
        bf16x8 v8 = *(const bf16x8*)(ep + (size_t)l * Hh + ln * 8);
        float s = 0.f;
        #pragma unroll
        for (int j = 0; j < 8; ++j)
            s += tanh_f(bf2f((ushort_t)v8[j]) + dp_r[j]) * va_r[j];
        #pragma unroll
        for (int o = 32; o; o >>= 1) s += __shfl_xor(s, o);
        if (ln == 0) es[l] = s;
    }
    __syncthreads();

    float v = (tid < Ll) ? es[tid] : -1e30f;
    float m = v;
    #pragma unroll
    for (int o = 32; o; o >>= 1) m = fmaxf(m, __shfl_xor(m, o));
    if (ln == 0) red[wv] = m;
    __syncthreads();
    m = red[0];
    #pragma unroll
    for (int i = 1; i < 8; ++i) m = fmaxf(m, red[i]);
    __syncthreads();
    float p = (tid < Ll) ? __expf(v - m) : 0.f;
    float s = p;
    #pragma unroll
    for (int o = 32; o; o >>= 1) s += __shfl_xor(s, o);
    if (ln == 0) red[wv] = s;
    __syncthreads();
    s = 0.f;
    #pragma unroll
    for (int i = 0; i < 8; ++i) s += red[i];
    float inv = 1.f / s;
    if (tid < Ll) {
        float a = p * inv;
        es[tid] = a;
        alphas[(size_t)b * alpha_stride + tid] = a;
    }
    if (tid < Ee) {
        float xv = emb[(size_t)captions[b * Tt + t] * Ee + tid];
        store_xh(xhi, xlo, b, tid, xv);
    }
    __syncthreads();

    // ctx: 8 waves; thread covers 8 e-cols (16B loads); l-ranges 25x4 + 24x4
    {
        const int g = wv, tl = ln;
        const int l0 = (g < 4) ? g * 25 : 100 + (g - 4) * 24;
        const int nl = (g < 4) ? 25 : 24;
        float a[8] = {};
        if (IMGBF) {
            const ushort_t* ib = img_bf + (size_t)b * Ll * ENCe + tl * 8;
            for (int i = 0; i < nl; ++i) {
                float al = es[l0 + i];
                bf16x8 u = *(const bf16x8*)(ib + (size_t)(l0 + i) * ENCe);
                #pragma unroll
                for (int j = 0; j < 8; ++j)
                    a[j] = fmaf(al, bf2f((ushort_t)u[j]), a[j]);
            }
        } else {
            const float* ib = img_f + (size_t)b * Ll * ENCe + tl * 8;
            for (int i = 0; i < nl; ++i) {
                float al = es[l0 + i];
                float4 u0 = *(const float4*)(ib + (size_t)(l0 + i) * ENCe);
                float4 u1 = *(const float4*)(ib + (size_t)(l0 + i) * ENCe + 4);
                a[0] = fmaf(al, u0.x, a[0]); a[1] = fmaf(al, u0.y, a[1]);
                a[2] = fmaf(al, u0.z, a[2]); a[3] = fmaf(al, u0.w, a[3]);
                a[4] = fmaf(al, u1.x, a[4]); a[5] = fmaf(al, u1.y, a[5]);
                a[6] = fmaf(al, u1.z, a[6]); a[7] = fmaf(al, u1.w, a[7]);
            }
        }
        #pragma unroll
        for (int j = 0; j < 8; j += 4) {
            f32x4 pv = (f32x4){a[j], a[j + 1], a[j + 2], a[j + 3]};
            *(f32x4*)&ctxp[g][tl * 8 + j] = pv;
        }
    }
    __syncthreads();

    {
        float cv = 0.f;
        #pragma unroll
        for (int g = 0; g < 8; ++g) cv += ctxp[g][tid];
        float xv = cv * dgb[b * 1024 + 512 + tid];
        store_xh(xhi, xlo, b, 256 + tid, xv);
    }
}

// gates GEMM (4-wave K-split, split-2) + fused LSTM, parallel epilogue
__global__ __launch_bounds__(256)
void ph_gates_k(LP P, int t)
{
    __shared__ f32x4 part[4][4][64];
    const int beta = blockIdx.x;
    const int tid = threadIdx.x, wv = tid >> 6, lane = tid & 63;
    const int jf = beta & 31, mq = beta >> 5;
    const int ks0 = wv * 10, lofs = lane * 8;
    constexpr int FS = 40 * 512;

    const ushort_t* paH = P.xhH + ((size_t)mq * 40 + ks0) * 512 + lofs;
    const ushort_t* paL = P.xhL + ((size_t)mq * 40 + ks0) * 512 + lofs;
    const ushort_t *pbH[4];
    #pragma unroll
    for (int g = 0; g < 4; ++g)
        pbH[g] = P.WgH + (size_t)(g * 32 + jf) * FS + (size_t)ks0 * 512 + lofs;

    f32x4 acc[4];
    #pragma unroll
    for (int g = 0; g < 4; ++g) acc[g] = (f32x4){0.f, 0.f, 0.f, 0.f};

    auto LOADF = [&](bf16x8 (&A)[2], bf16x8 (&B)[4], int i) {
        size_t o = (size_t)i * 512;
        A[0] = *(const bf16x8*)(paH + o);
        A[1] = *(const bf16x8*)(paL + o);
        #pragma unroll
        for (int g = 0; g < 4; ++g) B[g] = *(const bf16x8*)(pbH[g] + o);
    };
    auto COMPF = [&](bf16x8 (&A)[2], bf16x8 (&B)[4]) {
        #pragma unroll
        for (int g = 0; g < 4; ++g) {
            acc[g] = __builtin_amdgcn_mfma_f32_16x16x32_bf16(A[0], B[g], acc[g], 0, 0, 0);
            acc[g] = __builtin_amdgcn_mfma_f32_16x16x32_bf16(A[1], B[g], acc[g], 0, 0, 0);
        }
    };

    bf16x8 xA[2], xB[4], yA[2], yB[4];
    LOADF(xA, xB, 0);
    for (int i = 0; i < 10; i += 2) {
        LOADF(yA, yB, i + 1);
        COMPF(xA, xB);
        if (i + 2 < 10) LOADF(xA, xB, i + 2);
        COMPF(yA, yB);
    }

    #pragma unroll
    for (int g = 0; g < 4; ++g) part[wv][g][lane] = acc[g];
    __syncthreads();

    const int jl = tid & 15, bl = tid >> 4;
    const int lane2 = (bl >> 2) * 16 + jl, r2 = bl & 3;
    float g4[4];
    #pragma unroll
    for (int g = 0; g < 4; ++g)
        g4[g] = part[0][g][lane2][r2] + part[1][g][lane2][r2]
              + part[2][g][lane2][r2] + part[3][g][lane2][r2];

    const int j = jf * 16 + jl;
    const int b = mq * 16 + bl;
    float ig = sigm_f(g4[0] + P.bcomb[j]);
    float fg = sigm_f(g4[1] + P.bcomb[512 + j]);
    float gg = tanh_f(g4[2] + P.bcomb[1024 + j]);
    float og = sigm_f(g4[3] + P.bcomb[1536 + j]);
    float cn = fg * P.cbuf[b * 512 + j] + ig * gg;
    P.cbuf[b * 512 + j] = cn;
    float hv = og * tanh_f(cn);
    store_xh(P.xhH, P.xhL, b, 768 + j, hv);
    // hseq: hi only (logits GEMM is split-1 on A)
    size_t hidx = (((size_t)(t * 8 + (b >> 4)) * 16 + (j >> 5)) * 64
                   + ((j >> 3) & 3) * 16 + (b & 15)) * 8 + (j & 7);
    P.hsH[hidx] = f2bf(hv);
}

// ---------------------------------------------------------------------------
extern "C" void kernel_launch(void* const* d_in, const int* in_sizes, int n_in,
                              void* d_out, int out_size, void* d_ws, size_t ws_size,
                              hipStream_t stream)
{
    const float* img    = (const float*)d_in[0];
    const float* W_h    = (const float*)d_in[1];
    const float* b_h    = (const float*)d_in[2];
    const float* W_c    = (const float*)d_in[3];
    const float* b_c    = (const float*)d_in[4];
    const float* W_gate = (const float*)d_in[5];
    const float* b_gate = (const float*)d_in[6];
    const float* emb    = (const float*)d_in[7];
    const float* W_ae   = (const float*)d_in[8];
    const float* b_ae   = (const float*)d_in[9];
    const float* W_ad   = (const float*)d_in[10];
    const float* b_ad   = (const float*)d_in[11];
    const float* v_att  = (const float*)d_in[12];
    const float* W_ih   = (const float*)d_in[14];
    const float* b_ih   = (const float*)d_in[15];
    const float* W_hh   = (const float*)d_in[16];
    const float* b_hh   = (const float*)d_in[17];
    const float* W_out  = (const float*)d_in[18];
    const float* b_out  = (const float*)d_in[19];
    const int* captions = (const int*)d_in[20];

    float* out    = (float*)d_out;                       // [B,T,V]
    float* alphas = out + (size_t)Bb * Tt * Vv;          // [B,T,L]

    // ---- workspace allocator (256B aligned) ----
    char* p = (char*)d_ws;
    auto alloc = [&](size_t bytes) -> char* {
        char* r = p; p += (bytes + 255) & ~(size_t)255; return r;
    };
    const size_t szEnc   = (size_t)Bb * Ll * Hh * 2;
    const size_t szWout  = (size_t)625 * 16 * 512 * 2;
    const size_t szWg    = (size_t)128 * 40 * 512 * 2;
    const size_t szWdg   = (size_t)64 * 16 * 512 * 2;
    const size_t szWae   = (size_t)32 * 16 * 512 * 2;
    const size_t szXh    = (size_t)8 * 40 * 512 * 2;
    const size_t szHseq  = (size_t)160 * 16 * 512 * 2;
    const size_t szImg   = (size_t)Bb * Ll * ENCe * 2;

    ushort_t* enc_hi  = (ushort_t*)alloc(szEnc);
    ushort_t* WoutPkH = (ushort_t*)alloc(szWout);
    ushort_t* WgPkH   = (ushort_t*)alloc(szWg);
    ushort_t* WdgPkH  = (ushort_t*)alloc(szWdg);
    ushort_t* WaePkH  = (ushort_t*)alloc(szWae);
    ushort_t* xhPkH   = (ushort_t*)alloc(szXh);
    ushort_t* xhPkL   = (ushort_t*)alloc(szXh);
    ushort_t* hseqPkH = (ushort_t*)alloc(szHseq);
    float*    cbuf    = (float*)alloc((size_t)Bb * Hh * 4);
    float*    dgb     = (float*)alloc((size_t)Bb * 1024 * 4);
    float*    fm      = (float*)alloc((size_t)Bb * ENCe * 4);
    float*    bcomb   = (float*)alloc(4 * Hh * 4);

    auto tryAlloc = [&](size_t bytes) -> char* {
        size_t used = (size_t)(p - (char*)d_ws);
        size_t rounded = (bytes + 255) & ~(size_t)255;
        if (used + rounded > ws_size) return nullptr;
        return alloc(bytes);
    };
    ushort_t* imgLin = (ushort_t*)tryAlloc(szImg);
    ushort_t* imgPk  = (ushort_t*)tryAlloc(szImg);

    dim3 blk(256);
    const int NOSPLIT = 0x40000000;
    const int aFSh    = 16 * 512;

    // ---- setup: ONE mega kernel (conversions + featmean + bcomb) ----
    setup_mega_k<<<10564, blk, 0, stream>>>(
        W_out, W_ih, W_hh, W_ad, W_gate, W_ae,
        WoutPkH, WgPkH, WdgPkH, WaePkH,
        img, imgLin, imgPk, fm, b_ih, b_hh, bcomb);

    // h0 (packed xh) + c0 in one dispatch
    h0c0_k<<<dim3(16, 4), blk, 0, stream>>>(fm, W_h, b_h, W_c, b_c,
                                            xhPkH, xhPkL, cbuf);

    // enc_proj -> bf16 [B*L][512]
    if (imgPk && imgLin) {
        mgemm_pk<4, 4, 0, 0, 1, true, false, true, true, true><<<dim3(784), blk, 0, stream>>>(
            imgPk, nullptr, aFSh, WaePkH, nullptr, aFSh, b_ae, nullptr, NOSPLIT,
            enc_hi, Hh, 0, 32, Hh, 16, 4);
    } else {
        if (imgLin) convbf_k<<<2048, blk, 0, stream>>>(img, imgLin, (long long)Bb * Ll * ENCe);
        gemm_k<64, 4, 4, 0, 1><<<dim3(Hh / 64, (Bb * Ll) / 64), blk, 0, stream>>>(
            img, ENCe, W_ae, Hh, b_ae, enc_hi, Hh, Bb * Ll, Hh, ENCe);
    }

    // ---- 20-step loop: 3 dispatches per step ----
    LP P;
    P.WdgH = WdgPkH; P.WgH = WgPkH;
    P.b_ad = b_ad; P.b_gate = b_gate; P.bcomb = bcomb;
    P.dgb = dgb; P.cbuf = cbuf;
    P.xhH = xhPkH; P.xhL = xhPkL; P.hsH = hseqPkH;

    for (int t = 0; t < Tt; ++t) {
        ph_dg_k<<<256, blk, 0, stream>>>(P);
        if (imgLin)
            attn_fused_k<true ><<<Bb, dim3(512), 0, stream>>>(
                enc_hi, dgb, v_att, imgLin, nullptr, emb, captions,
                alphas + (size_t)t * Ll, (long long)Tt * Ll, xhPkH, xhPkL, t);
        else
            attn_fused_k<false><<<Bb, dim3(512), 0, stream>>>(
                enc_hi, dgb, v_att, nullptr, img, emb, captions,
                alphas + (size_t)t * Ll, (long long)Tt * Ll, xhPkH, xhPkL, t);
        ph_gates_k<<<256, blk, 0, stream>>>(P, t);
    }

    // ---- batched logits (split-1: hseq hi only) -> out[b][t][v] ----
    mgemm_pk<4, 4, 0, 0, 1, false, true, true, false, true><<<dim3(79 * 20), blk, 0, stream>>>(
        hseqPkH, nullptr, aFSh, WoutPkH, nullptr, aFSh,
        b_out, nullptr, NOSPLIT, out, (long long)Tt * Vv, (long long)Vv,
        625, Vv, 16, 20);
}